// Round 5
// baseline (328.762 us; speedup 1.0000x reference)
//
#include <hip/hip_runtime.h>
#include <hip/hip_bf16.h>

typedef __attribute__((ext_vector_type(8))) short short8;
typedef __attribute__((ext_vector_type(4))) float f32x4;
typedef __attribute__((ext_vector_type(4))) unsigned uintx4;

#define B_  32
#define S_  484
#define E_  1024
#define NH  16
#define SP  512          // padded sequence length
#define M_  (B_*S_)      // 15488 = 121*128

static __device__ __forceinline__ ushort f2bf(float f) {
  union { float f; unsigned u; } v; v.f = f;
  unsigned u = v.u;
  return (ushort)((u + 0x7FFFu + ((u >> 16) & 1u)) >> 16);
}

static __device__ __forceinline__ unsigned cvt_pk_bf16(float lo, float hi) {
  unsigned r;
  asm("v_cvt_pk_bf16_f32 %0, %1, %2" : "=v"(r) : "v"(lo), "v"(hi));
  return r;
}

#define GLOAD_LDS16(gp, lp) \
  __builtin_amdgcn_global_load_lds((const __attribute__((address_space(1))) void*)(gp), \
                                   (__attribute__((address_space(3))) void*)(lp), 16, 0, 0)

// ---------------- weight transpose + convert: WT[n][k] = W[k][n] ----------------
__global__ __launch_bounds__(256)
void transpose_convert(const float* __restrict__ W, ushort* __restrict__ WT, int K, int N) {
  __shared__ float tile[32][33];
  int k0 = blockIdx.y * 32, n0 = blockIdx.x * 32;
  int tx = threadIdx.x, ty = threadIdx.y;   // 32 x 8
  for (int i = ty; i < 32; i += 8) tile[i][tx] = W[(size_t)(k0 + i) * N + n0 + tx];
  __syncthreads();
  for (int i = ty; i < 32; i += 8) WT[(size_t)(n0 + i) * K + k0 + tx] = f2bf(tile[tx][i]);
}

// ---------------- bf16 GEMM, B^T input, 128x128 tile ----------------
// AF32: A is f32, reg-staged (load float4 -> cvt_pk -> ds_write); else bf16 via global_load_lds.
// EPI 0: bf16 out (scaled), layout ((b*HN + h)*SP + pos)*64 + d   [SWZ: d ^= (pos&7)<<3]
// EPI 1: bf16 out (V), layout ((b*HN+h)*64 + d)*SP + permuted pos [SWZ: sigma + granule xor]
// EPI 2: f32 out, row-major [M][N]
template<int EPI, int SWZ, int AF32>
__global__ __launch_bounds__(256)
void gemm_bt(const void* __restrict__ Ain, const ushort* __restrict__ BT,
             void* __restrict__ Cout, int N, int K, int HN, float oscale) {
  __shared__ alignas(16) ushort sA[2][128 * 32];
  __shared__ alignas(16) ushort sB[2][128 * 32];
  const int tid = threadIdx.x;
  const int lane = tid & 63, w = tid >> 6;
  const int m0 = blockIdx.y * 128, n0 = blockIdx.x * 128;
  const int NK = K >> 5;

  const int srow = w * 32 + (lane >> 2);
  const int scol = (lane & 3) * 8;
  const ushort* gB0 = BT + (size_t)(n0 + srow) * K + scol;

  // A staging pointers (both computed; only one path used per instantiation)
  const ushort* gA0bf = (const ushort*)Ain + (size_t)(m0 + srow) * K + scol;
  const int arow = w * 32 + (lane >> 1);     // AF32: 32 rows/wave, 2 lanes/row
  const int acol = (lane & 1) * 16;          // 16 floats per lane
  const float* gA0f = (const float*)Ain + (size_t)(m0 + arow) * K + acol;

  const int wr = w >> 1, wc = w & 1;          // 2x2 wave grid, each 64x64
  const int g4 = lane >> 4, l16 = lane & 15;
  const int aoff = (wr * 64 + l16) * 32 + 8 * g4;
  const int boff = (wc * 64 + l16) * 32 + 8 * g4;

  f32x4 acc[4][4] = {};
  float4 fA0, fA1, fA2, fA3;

  auto issueA = [&](int kt) {
    const float4* p = (const float4*)(gA0f + kt * 32);
    fA0 = p[0]; fA1 = p[1]; fA2 = p[2]; fA3 = p[3];
  };
  auto writeA = [&](int buf) {
    unsigned d0 = cvt_pk_bf16(fA0.x, fA0.y), d1 = cvt_pk_bf16(fA0.z, fA0.w);
    unsigned d2 = cvt_pk_bf16(fA1.x, fA1.y), d3 = cvt_pk_bf16(fA1.z, fA1.w);
    unsigned d4 = cvt_pk_bf16(fA2.x, fA2.y), d5 = cvt_pk_bf16(fA2.z, fA2.w);
    unsigned d6 = cvt_pk_bf16(fA3.x, fA3.y), d7 = cvt_pk_bf16(fA3.z, fA3.w);
    ushort* dst = &sA[buf][arow * 32 + acol];
    uintx4 q0 = {d0, d1, d2, d3}, q1 = {d4, d5, d6, d7};
    *(uintx4*)dst = q0;
    *(uintx4*)(dst + 8) = q1;
  };

  // prologue: stage k-tile 0 into buf 0
  if (AF32) issueA(0);
  else {
    GLOAD_LDS16(gA0bf,          &sA[0][(w * 32) * 32]);
    GLOAD_LDS16(gA0bf + 16 * K, &sA[0][(w * 32 + 16) * 32]);
  }
  GLOAD_LDS16(gB0,          &sB[0][(w * 32) * 32]);
  GLOAD_LDS16(gB0 + 16 * K, &sB[0][(w * 32 + 16) * 32]);
  if (AF32) writeA(0);

  for (int kt = 0; kt < NK; ++kt) {
    __syncthreads();   // publishes tile kt (vmcnt+lgkm drained); buf[nb] free
    const int nb = (kt + 1) & 1;
    if (kt + 1 < NK) {
      const ushort* gb = gB0 + (kt + 1) * 32;
      GLOAD_LDS16(gb,          &sB[nb][(w * 32) * 32]);
      GLOAD_LDS16(gb + 16 * K, &sB[nb][(w * 32 + 16) * 32]);
      if (AF32) issueA(kt + 1);
      else {
        const ushort* ga = gA0bf + (kt + 1) * 32;
        GLOAD_LDS16(ga,          &sA[nb][(w * 32) * 32]);
        GLOAD_LDS16(ga + 16 * K, &sA[nb][(w * 32 + 16) * 32]);
      }
    }
    const ushort* pa = &sA[kt & 1][aoff];
    const ushort* pb = &sB[kt & 1][boff];
    short8 af[4], bf[4];
#pragma unroll
    for (int i = 0; i < 4; ++i) {
      af[i] = *(const short8*)(pa + i * 16 * 32);
      bf[i] = *(const short8*)(pb + i * 16 * 32);
    }
#pragma unroll
    for (int mi = 0; mi < 4; ++mi)
#pragma unroll
      for (int ni = 0; ni < 4; ++ni)
        acc[mi][ni] = __builtin_amdgcn_mfma_f32_16x16x32_bf16(af[mi], bf[ni], acc[mi][ni], 0, 0, 0);
    if (AF32 && kt + 1 < NK) writeA(nb);   // cvt+LDS-write after MFMAs (loads landed under compute)
  }

#pragma unroll
  for (int mi = 0; mi < 4; ++mi) {
#pragma unroll
    for (int ni = 0; ni < 4; ++ni) {
#pragma unroll
      for (int r = 0; r < 4; ++r) {
        int m = m0 + wr * 64 + mi * 16 + g4 * 4 + r;
        int n = n0 + wc * 64 + ni * 16 + l16;
        float vv = acc[mi][ni][r];
        if (EPI == 2) {
          ((float*)Cout)[(size_t)m * N + n] = vv;
        } else {
          int b = m / S_, pos = m % S_;
          if (EPI == 0) {
            int dd = n & 63;
            if (SWZ) dd ^= (pos & 7) << 3;      // K-LDS row bank swizzle
            ushort hv = f2bf(vv * oscale);
            ((ushort*)Cout)[(((size_t)b * HN + (n >> 6)) * SP + pos) * 64 + dd] = hv;
          } else {
            // V: permute k within 32-window (sigma = pi^-1: p<16 -> 2p, else 2(p-16)+1)
            int local = pos & 31;
            int j = (local < 16) ? (2 * local) : (2 * local - 31);
            int pf_ = (pos & ~31) | (j ^ ((n & 3) << 3));   // + granule bank swizzle
            ushort hv = f2bf(vv);
            ((ushort*)Cout)[(((size_t)b * HN + (n >> 6)) * 64 + (n & 63)) * SP + pf_] = hv;
          }
        }
      }
    }
  }
}

// ---------------- fused GQA attention: LDS-staged K/V, packed P path ----------------
// 1D grid 4096, XCD swizzle; block 256 = 4 waves, wave = 16 q-rows
// qp pre-scaled by 0.125*log2e; p = exp2(s + bias'); P/V share k-permutation pi
__global__ __launch_bounds__(256)
void attn_kernel(const ushort* __restrict__ qp, const ushort* __restrict__ kp,
                 const ushort* __restrict__ vpT, const float* __restrict__ rel,
                 ushort* __restrict__ ao) {
  __shared__ float sBias[1056];                   // +32 guard offset (idx range [4,1042])
  __shared__ alignas(16) ushort sK[2][32 * 64];   // [krow][d], bank-swizzled at producer
  __shared__ alignas(16) ushort sV[2][64 * 32];   // [d][k-window], sigma-permuted + swizzled
  __shared__ alignas(16) ushort sP[4][16 * 40];
  const int tid = threadIdx.x;
  const int blk = blockIdx.x;
  const int logical = (blk & 7) * 512 + (blk >> 3);     // bijective (4096 = 8*512)
  const int qt = logical & 7, head = (logical >> 3) & 15, b = logical >> 7;
  const int g = head >> 2;
  const float LOG2E = 1.44269504f;
  for (int t = tid; t < 1056; t += 256)
    sBias[t] = (t >= 32 && t < 999) ? rel[(t - 32) * 16 + head] * LOG2E : -1e30f;

  const int lane = tid & 63, w = tid >> 6;
  const int g4 = lane >> 4, l16 = lane & 15;
  const int qw = qt * 64 + w * 16;

  const ushort* qbase = qp + (((size_t)b * NH + head) * SP + qw + l16) * 64;
  short8 qf0 = *(const short8*)(qbase + 8 * g4);
  short8 qf1 = *(const short8*)(qbase + 32 + 8 * g4);

  // staging source pointers (linear copy of pre-swizzled layouts)
  const ushort* kSrc = kp  + ((size_t)b * 4 + g) * SP * 64 + (tid >> 3) * 64 + (tid & 7) * 8;
  const ushort* vSrc = vpT + ((size_t)b * 4 + g) * 64 * SP + (tid >> 2) * SP + (tid & 3) * 8;

  f32x4 acc[4] = {};
  float ps[4] = {0.f, 0.f, 0.f, 0.f};
  const int ib = l16 - (qw + g4 * 4) + 483 + 32;   // bias idx (incl. guard offset)
  ushort* sPw = &sP[w][0];

  // fragment LDS offsets (element units)
  const int kswz  = (l16 & 7) << 3;
  const int kOff0 = l16 * 64 + ((8 * g4) ^ kswz);
  const int kOff1 = l16 * 64 + ((32 + 8 * g4) ^ kswz);
  const int vOff  = l16 * 32 + 8 * (g4 ^ (l16 & 3));     // + nt*16*32

  GLOAD_LDS16(kSrc, &sK[0][w * 512]);
  GLOAD_LDS16(vSrc, &sV[0][w * 512]);

  for (int kt = 0; kt < 16; ++kt) {
    __syncthreads();                 // tile kt staged; buf[(kt+1)&1] free
    if (kt + 1 < 16) {
      GLOAD_LDS16(kSrc + (kt + 1) * 2048, &sK[(kt + 1) & 1][w * 512]);
      GLOAD_LDS16(vSrc + (kt + 1) * 32,   &sV[(kt + 1) & 1][w * 512]);
    }
    const ushort* sk = &sK[kt & 1][0];
    const ushort* sv = &sV[kt & 1][0];
    short8 kf0 = *(const short8*)(sk + kOff0);
    short8 kf1 = *(const short8*)(sk + kOff1);
    short8 kf2 = *(const short8*)(sk + 1024 + kOff0);
    short8 kf3 = *(const short8*)(sk + 1024 + kOff1);
    f32x4 s0 = {}, s1 = {};
    s0 = __builtin_amdgcn_mfma_f32_16x16x32_bf16(qf0, kf0, s0, 0, 0, 0);
    s0 = __builtin_amdgcn_mfma_f32_16x16x32_bf16(qf1, kf1, s0, 0, 0, 0);
    s1 = __builtin_amdgcn_mfma_f32_16x16x32_bf16(qf0, kf2, s1, 0, 0, 0);
    s1 = __builtin_amdgcn_mfma_f32_16x16x32_bf16(qf1, kf3, s1, 0, 0, 0);

    const int k0 = kt * 32;
#pragma unroll
    for (int r = 0; r < 4; ++r) {
      int i0 = ib + k0 - r;
      float p0 = __builtin_amdgcn_exp2f(s0[r] + sBias[i0]);
      float p1 = __builtin_amdgcn_exp2f(s1[r] + sBias[i0 + 16]);
      if (kt == 15) {                       // mask BEFORE store: pad P == 0 exactly
        p0 = (k0 + l16 < S_) ? p0 : 0.f;
        p1 = (k0 + 16 + l16 < S_) ? p1 : 0.f;
      }
      ps[r] += p0 + p1;
      // packed store: row e=2j holds k=j (p0), e=2j+1 holds k=j+16 (p1)  [pi]
      *(unsigned*)(sPw + (g4 * 4 + r) * 40 + 2 * l16) = cvt_pk_bf16(p0, p1);
    }
    short8 pf = *(const short8*)(sPw + l16 * 40 + 8 * g4);
#pragma unroll
    for (int nt = 0; nt < 4; ++nt) {
      short8 vf = *(const short8*)(sv + vOff + nt * 512);   // V rows sigma-permuted: matches pi
      acc[nt] = __builtin_amdgcn_mfma_f32_16x16x32_bf16(pf, vf, acc[nt], 0, 0, 0);
    }
  }

  // row-sum reduce across the 16-lane group (once, outside the k-loop)
#pragma unroll
  for (int off = 1; off < 16; off <<= 1) {
#pragma unroll
    for (int r = 0; r < 4; ++r) ps[r] += __shfl_xor(ps[r], off, 64);
  }

#pragma unroll
  for (int r = 0; r < 4; ++r) {
    int q_abs = qw + g4 * 4 + r;
    if (q_abs < S_) {
      float inv = 1.f / ps[r];
#pragma unroll
      for (int nt = 0; nt < 4; ++nt) {
        int dd = nt * 16 + l16;
        ao[((size_t)b * S_ + q_abs) * 1024 + head * 64 + dd] = f2bf(acc[nt][r] * inv);
      }
    }
  }
}

extern "C" void kernel_launch(void* const* d_in, const int* in_sizes, int n_in,
                              void* d_out, int out_size, void* d_ws, size_t ws_size,
                              hipStream_t stream) {
  const float* query = (const float*)d_in[0];
  const float* key   = (const float*)d_in[1];
  const float* value = (const float*)d_in[2];
  const float* Wq    = (const float*)d_in[3];
  const float* Wk    = (const float*)d_in[4];
  const float* Wv    = (const float*)d_in[5];
  const float* Wo    = (const float*)d_in[6];
  const float* rel   = (const float*)d_in[7];

  char* ws = (char*)d_ws;
  size_t off = 0;
  auto alloc = [&](size_t bytes) { char* p = ws + off; off += (bytes + 255) & ~(size_t)255; return p; };

  const size_t MEelems = (size_t)M_ * E_;             // 15,859,712
  ushort* wqT = (ushort*)alloc((size_t)1024 * 1024 * 2);
  ushort* wkT = (ushort*)alloc((size_t)256 * 1024 * 2);
  ushort* wvT = (ushort*)alloc((size_t)256 * 1024 * 2);
  ushort* woT = (ushort*)alloc((size_t)1024 * 1024 * 2);
  ushort* qp  = (ushort*)alloc((size_t)B_ * NH * SP * 64 * 2);   // 32 MB
  ushort* kp  = (ushort*)alloc((size_t)B_ * 4 * SP * 64 * 2);    // 8 MB
  ushort* vp  = (ushort*)alloc((size_t)B_ * 4 * 64 * SP * 2);    // 8 MB
  ushort* ao  = (ushort*)alloc(MEelems * 2);

  transpose_convert<<<dim3(32, 32), dim3(32, 8), 0, stream>>>(Wq, wqT, 1024, 1024);
  transpose_convert<<<dim3(8, 32),  dim3(32, 8), 0, stream>>>(Wk, wkT, 1024, 256);
  transpose_convert<<<dim3(8, 32),  dim3(32, 8), 0, stream>>>(Wv, wvT, 1024, 256);
  transpose_convert<<<dim3(32, 32), dim3(32, 8), 0, stream>>>(Wo, woT, 1024, 1024);

  const float QSCALE = 0.125f * 1.44269504f;   // fold 1/sqrt(D) and log2e into q
  gemm_bt<0,0,1><<<dim3(8, 121), 256, 0, stream>>>(query, wqT, qp, 1024, 1024, NH, QSCALE);
  gemm_bt<0,1,1><<<dim3(2, 121), 256, 0, stream>>>(key,   wkT, kp, 256, 1024, 4, 1.0f);
  gemm_bt<1,1,1><<<dim3(2, 121), 256, 0, stream>>>(value, wvT, vp, 256, 1024, 4, 1.0f);

  attn_kernel<<<4096, 256, 0, stream>>>(qp, kp, vp, rel, ao);

  gemm_bt<2,0,0><<<dim3(8, 121), 256, 0, stream>>>(ao, woT, d_out, 1024, 1024, 0, 1.0f);
}

// Round 6
// 305.579 us; speedup vs baseline: 1.0759x; 1.0759x over previous
//
#include <hip/hip_runtime.h>
#include <hip/hip_bf16.h>

typedef __attribute__((ext_vector_type(8))) short short8;
typedef __attribute__((ext_vector_type(4))) float f32x4;
typedef __attribute__((ext_vector_type(4))) unsigned uintx4;

#define B_  32
#define S_  484
#define E_  1024
#define NH  16
#define SP  512          // padded sequence length
#define M_  (B_*S_)      // 15488 = 121*128

static __device__ __forceinline__ ushort f2bf(float f) {
  union { float f; unsigned u; } v; v.f = f;
  unsigned u = v.u;
  return (ushort)((u + 0x7FFFu + ((u >> 16) & 1u)) >> 16);
}

static __device__ __forceinline__ unsigned cvt_pk_bf16(float lo, float hi) {
  unsigned r;
  asm("v_cvt_pk_bf16_f32 %0, %1, %2" : "=v"(r) : "v"(lo), "v"(hi));
  return r;
}

#define GLOAD_LDS16(gp, lp) \
  __builtin_amdgcn_global_load_lds((const __attribute__((address_space(1))) void*)(gp), \
                                   (__attribute__((address_space(3))) void*)(lp), 16, 0, 0)

// ---------------- weight transpose + convert: WT[n][k] = W[k][n] ----------------
__global__ __launch_bounds__(256)
void transpose_convert(const float* __restrict__ W, ushort* __restrict__ WT, int K, int N) {
  __shared__ float tile[32][33];
  int k0 = blockIdx.y * 32, n0 = blockIdx.x * 32;
  int tx = threadIdx.x, ty = threadIdx.y;   // 32 x 8
  for (int i = ty; i < 32; i += 8) tile[i][tx] = W[(size_t)(k0 + i) * N + n0 + tx];
  __syncthreads();
  for (int i = ty; i < 32; i += 8) WT[(size_t)(n0 + i) * K + k0 + tx] = f2bf(tile[tx][i]);
}

// ---------------- bf16 GEMM, B^T input, 128x128 tile, XCD-chunked 1D grid ----------------
// Grid is 1D; logical = chunked-bijective map so all NX n-blocks of one m-slab
// land on ONE XCD (A-panel L2 reuse). NXLOG = log2(#n-blocks).
// AF32: A is f32, reg-staged (float4 -> cvt_pk -> ds_write); else bf16 global_load_lds.
// EPI 0: bf16 out (scaled), ((b*HN+h)*SP + pos)*64 + d   [SWZ: d ^= (pos&7)<<3]
// EPI 1: bf16 out (V), ((b*HN+h)*64 + d)*SP + permuted pos [SWZ: sigma + granule xor]
// EPI 2: f32 out, row-major [M][N]
template<int EPI, int SWZ, int AF32, int NXLOG>
__global__ __launch_bounds__(256)
void gemm_bt(const void* __restrict__ Ain, const ushort* __restrict__ BT,
             void* __restrict__ Cout, int N, int K, int HN, float oscale) {
  __shared__ alignas(16) ushort sA[2][128 * 32];
  __shared__ alignas(16) ushort sB[2][128 * 32];
  const int tid = threadIdx.x;
  const int lane = tid & 63, w = tid >> 6;

  // chunked bijective XCD swizzle (nwg need not be %8==0)
  const int nwg = gridDim.x;
  const int qq = nwg >> 3, rr = nwg & 7;
  const int x = blockIdx.x & 7, seq = blockIdx.x >> 3;
  const int logical = x * qq + (x < rr ? x : rr) + seq;
  const int m0 = (logical >> NXLOG) * 128;
  const int n0 = (logical & ((1 << NXLOG) - 1)) * 128;
  const int NK = K >> 5;

  const int srow = w * 32 + (lane >> 2);
  const int scol = (lane & 3) * 8;
  const ushort* gB0 = BT + (size_t)(n0 + srow) * K + scol;

  const ushort* gA0bf = (const ushort*)Ain + (size_t)(m0 + srow) * K + scol;
  const int arow = w * 32 + (lane >> 1);     // AF32: 32 rows/wave, 2 lanes/row
  const int acol = (lane & 1) * 16;          // 16 floats per lane
  const float* gA0f = (const float*)Ain + (size_t)(m0 + arow) * K + acol;

  const int wr = w >> 1, wc = w & 1;          // 2x2 wave grid, each 64x64
  const int g4 = lane >> 4, l16 = lane & 15;
  const int aoff = (wr * 64 + l16) * 32 + 8 * g4;
  const int boff = (wc * 64 + l16) * 32 + 8 * g4;

  f32x4 acc[4][4] = {};
  float4 fA0, fA1, fA2, fA3;

  auto issueA = [&](int kt) {
    const float4* p = (const float4*)(gA0f + kt * 32);
    fA0 = p[0]; fA1 = p[1]; fA2 = p[2]; fA3 = p[3];
  };
  auto writeA = [&](int buf) {
    unsigned d0 = cvt_pk_bf16(fA0.x, fA0.y), d1 = cvt_pk_bf16(fA0.z, fA0.w);
    unsigned d2 = cvt_pk_bf16(fA1.x, fA1.y), d3 = cvt_pk_bf16(fA1.z, fA1.w);
    unsigned d4 = cvt_pk_bf16(fA2.x, fA2.y), d5 = cvt_pk_bf16(fA2.z, fA2.w);
    unsigned d6 = cvt_pk_bf16(fA3.x, fA3.y), d7 = cvt_pk_bf16(fA3.z, fA3.w);
    ushort* dst = &sA[buf][arow * 32 + acol];
    uintx4 q0 = {d0, d1, d2, d3}, q1 = {d4, d5, d6, d7};
    *(uintx4*)dst = q0;
    *(uintx4*)(dst + 8) = q1;
  };

  if (AF32) issueA(0);
  else {
    GLOAD_LDS16(gA0bf,          &sA[0][(w * 32) * 32]);
    GLOAD_LDS16(gA0bf + 16 * K, &sA[0][(w * 32 + 16) * 32]);
  }
  GLOAD_LDS16(gB0,          &sB[0][(w * 32) * 32]);
  GLOAD_LDS16(gB0 + 16 * K, &sB[0][(w * 32 + 16) * 32]);
  if (AF32) writeA(0);

  for (int kt = 0; kt < NK; ++kt) {
    __syncthreads();   // publishes tile kt; buf[nb] free
    const int nb = (kt + 1) & 1;
    if (kt + 1 < NK) {
      const ushort* gb = gB0 + (kt + 1) * 32;
      GLOAD_LDS16(gb,          &sB[nb][(w * 32) * 32]);
      GLOAD_LDS16(gb + 16 * K, &sB[nb][(w * 32 + 16) * 32]);
      if (AF32) issueA(kt + 1);
      else {
        const ushort* ga = gA0bf + (kt + 1) * 32;
        GLOAD_LDS16(ga,          &sA[nb][(w * 32) * 32]);
        GLOAD_LDS16(ga + 16 * K, &sA[nb][(w * 32 + 16) * 32]);
      }
    }
    const ushort* pa = &sA[kt & 1][aoff];
    const ushort* pb = &sB[kt & 1][boff];
    short8 af[4], bf[4];
#pragma unroll
    for (int i = 0; i < 4; ++i) {
      af[i] = *(const short8*)(pa + i * 16 * 32);
      bf[i] = *(const short8*)(pb + i * 16 * 32);
    }
#pragma unroll
    for (int mi = 0; mi < 4; ++mi)
#pragma unroll
      for (int ni = 0; ni < 4; ++ni)
        acc[mi][ni] = __builtin_amdgcn_mfma_f32_16x16x32_bf16(af[mi], bf[ni], acc[mi][ni], 0, 0, 0);
    if (AF32 && kt + 1 < NK) writeA(nb);   // cvt+write after MFMAs (loads landed under compute)
  }

#pragma unroll
  for (int mi = 0; mi < 4; ++mi) {
#pragma unroll
    for (int ni = 0; ni < 4; ++ni) {
#pragma unroll
      for (int r = 0; r < 4; ++r) {
        int m = m0 + wr * 64 + mi * 16 + g4 * 4 + r;
        int n = n0 + wc * 64 + ni * 16 + l16;
        float vv = acc[mi][ni][r];
        if (EPI == 2) {
          ((float*)Cout)[(size_t)m * N + n] = vv;
        } else {
          int b = m / S_, pos = m % S_;
          if (EPI == 0) {
            int dd = n & 63;
            if (SWZ) dd ^= (pos & 7) << 3;      // K-LDS row bank swizzle
            ushort hv = f2bf(vv * oscale);
            ((ushort*)Cout)[(((size_t)b * HN + (n >> 6)) * SP + pos) * 64 + dd] = hv;
          } else {
            // V: permute k within 32-window (sigma = pi^-1: p<16 -> 2p, else 2(p-16)+1)
            int local = pos & 31;
            int j = (local < 16) ? (2 * local) : (2 * local - 31);
            int pf_ = (pos & ~31) | (j ^ ((n & 3) << 3));   // + granule bank swizzle
            ushort hv = f2bf(vv);
            ((ushort*)Cout)[(((size_t)b * HN + (n >> 6)) * 64 + (n & 63)) * SP + pf_] = hv;
          }
        }
      }
    }
  }
}

// ---------------- fused GQA attention: LDS-staged K/V, packed P path ----------------
__global__ __launch_bounds__(256)
void attn_kernel(const ushort* __restrict__ qp, const ushort* __restrict__ kp,
                 const ushort* __restrict__ vpT, const float* __restrict__ rel,
                 ushort* __restrict__ ao) {
  __shared__ float sBias[1056];                   // +32 guard offset
  __shared__ alignas(16) ushort sK[2][32 * 64];
  __shared__ alignas(16) ushort sV[2][64 * 32];
  __shared__ alignas(16) ushort sP[4][16 * 40];
  const int tid = threadIdx.x;
  const int blk = blockIdx.x;
  const int logical = (blk & 7) * 512 + (blk >> 3);     // bijective (4096 = 8*512)
  const int qt = logical & 7, head = (logical >> 3) & 15, b = logical >> 7;
  const int g = head >> 2;
  const float LOG2E = 1.44269504f;
  for (int t = tid; t < 1056; t += 256)
    sBias[t] = (t >= 32 && t < 999) ? rel[(t - 32) * 16 + head] * LOG2E : -1e30f;

  const int lane = tid & 63, w = tid >> 6;
  const int g4 = lane >> 4, l16 = lane & 15;
  const int qw = qt * 64 + w * 16;

  const ushort* qbase = qp + (((size_t)b * NH + head) * SP + qw + l16) * 64;
  short8 qf0 = *(const short8*)(qbase + 8 * g4);
  short8 qf1 = *(const short8*)(qbase + 32 + 8 * g4);

  const ushort* kSrc = kp  + ((size_t)b * 4 + g) * SP * 64 + (tid >> 3) * 64 + (tid & 7) * 8;
  const ushort* vSrc = vpT + ((size_t)b * 4 + g) * 64 * SP + (tid >> 2) * SP + (tid & 3) * 8;

  f32x4 acc[4] = {};
  float ps[4] = {0.f, 0.f, 0.f, 0.f};
  const int ib = l16 - (qw + g4 * 4) + 483 + 32;
  ushort* sPw = &sP[w][0];

  const int kswz  = (l16 & 7) << 3;
  const int kOff0 = l16 * 64 + ((8 * g4) ^ kswz);
  const int kOff1 = l16 * 64 + ((32 + 8 * g4) ^ kswz);
  const int vOff  = l16 * 32 + 8 * (g4 ^ (l16 & 3));

  GLOAD_LDS16(kSrc, &sK[0][w * 512]);
  GLOAD_LDS16(vSrc, &sV[0][w * 512]);

  for (int kt = 0; kt < 16; ++kt) {
    __syncthreads();
    if (kt + 1 < 16) {
      GLOAD_LDS16(kSrc + (kt + 1) * 2048, &sK[(kt + 1) & 1][w * 512]);
      GLOAD_LDS16(vSrc + (kt + 1) * 32,   &sV[(kt + 1) & 1][w * 512]);
    }
    const ushort* sk = &sK[kt & 1][0];
    const ushort* sv = &sV[kt & 1][0];
    short8 kf0 = *(const short8*)(sk + kOff0);
    short8 kf1 = *(const short8*)(sk + kOff1);
    short8 kf2 = *(const short8*)(sk + 1024 + kOff0);
    short8 kf3 = *(const short8*)(sk + 1024 + kOff1);
    f32x4 s0 = {}, s1 = {};
    s0 = __builtin_amdgcn_mfma_f32_16x16x32_bf16(qf0, kf0, s0, 0, 0, 0);
    s0 = __builtin_amdgcn_mfma_f32_16x16x32_bf16(qf1, kf1, s0, 0, 0, 0);
    s1 = __builtin_amdgcn_mfma_f32_16x16x32_bf16(qf0, kf2, s1, 0, 0, 0);
    s1 = __builtin_amdgcn_mfma_f32_16x16x32_bf16(qf1, kf3, s1, 0, 0, 0);

    const int k0 = kt * 32;
#pragma unroll
    for (int r = 0; r < 4; ++r) {
      int i0 = ib + k0 - r;
      float p0 = __builtin_amdgcn_exp2f(s0[r] + sBias[i0]);
      float p1 = __builtin_amdgcn_exp2f(s1[r] + sBias[i0 + 16]);
      if (kt == 15) {                       // mask BEFORE store: pad P == 0 exactly
        p0 = (k0 + l16 < S_) ? p0 : 0.f;
        p1 = (k0 + 16 + l16 < S_) ? p1 : 0.f;
      }
      ps[r] += p0 + p1;
      *(unsigned*)(sPw + (g4 * 4 + r) * 40 + 2 * l16) = cvt_pk_bf16(p0, p1);
    }
    short8 pf = *(const short8*)(sPw + l16 * 40 + 8 * g4);
#pragma unroll
    for (int nt = 0; nt < 4; ++nt) {
      short8 vf = *(const short8*)(sv + vOff + nt * 512);
      acc[nt] = __builtin_amdgcn_mfma_f32_16x16x32_bf16(pf, vf, acc[nt], 0, 0, 0);
    }
  }

#pragma unroll
  for (int off = 1; off < 16; off <<= 1) {
#pragma unroll
    for (int r = 0; r < 4; ++r) ps[r] += __shfl_xor(ps[r], off, 64);
  }

#pragma unroll
  for (int r = 0; r < 4; ++r) {
    int q_abs = qw + g4 * 4 + r;
    if (q_abs < S_) {
      float inv = 1.f / ps[r];
#pragma unroll
      for (int nt = 0; nt < 4; ++nt) {
        int dd = nt * 16 + l16;
        ao[((size_t)b * S_ + q_abs) * 1024 + head * 64 + dd] = f2bf(acc[nt][r] * inv);
      }
    }
  }
}

extern "C" void kernel_launch(void* const* d_in, const int* in_sizes, int n_in,
                              void* d_out, int out_size, void* d_ws, size_t ws_size,
                              hipStream_t stream) {
  const float* query = (const float*)d_in[0];
  const float* key   = (const float*)d_in[1];
  const float* value = (const float*)d_in[2];
  const float* Wq    = (const float*)d_in[3];
  const float* Wk    = (const float*)d_in[4];
  const float* Wv    = (const float*)d_in[5];
  const float* Wo    = (const float*)d_in[6];
  const float* rel   = (const float*)d_in[7];

  char* ws = (char*)d_ws;
  size_t off = 0;
  auto alloc = [&](size_t bytes) { char* p = ws + off; off += (bytes + 255) & ~(size_t)255; return p; };

  const size_t MEelems = (size_t)M_ * E_;             // 15,859,712
  ushort* wqT = (ushort*)alloc((size_t)1024 * 1024 * 2);
  ushort* wkT = (ushort*)alloc((size_t)256 * 1024 * 2);
  ushort* wvT = (ushort*)alloc((size_t)256 * 1024 * 2);
  ushort* woT = (ushort*)alloc((size_t)1024 * 1024 * 2);
  ushort* qp  = (ushort*)alloc((size_t)B_ * NH * SP * 64 * 2);   // 32 MB
  ushort* kp  = (ushort*)alloc((size_t)B_ * 4 * SP * 64 * 2);    // 8 MB
  ushort* vp  = (ushort*)alloc((size_t)B_ * 4 * 64 * SP * 2);    // 8 MB
  ushort* ao  = (ushort*)alloc(MEelems * 2);

  transpose_convert<<<dim3(32, 32), dim3(32, 8), 0, stream>>>(Wq, wqT, 1024, 1024);
  transpose_convert<<<dim3(8, 32),  dim3(32, 8), 0, stream>>>(Wk, wkT, 1024, 256);
  transpose_convert<<<dim3(8, 32),  dim3(32, 8), 0, stream>>>(Wv, wvT, 1024, 256);
  transpose_convert<<<dim3(32, 32), dim3(32, 8), 0, stream>>>(Wo, woT, 1024, 1024);

  const float QSCALE = 0.125f * 1.44269504f;   // fold 1/sqrt(D) and log2e into q
  gemm_bt<0,0,1,3><<<968, 256, 0, stream>>>(query, wqT, qp, 1024, 1024, NH, QSCALE);
  gemm_bt<0,1,1,1><<<242, 256, 0, stream>>>(key,   wkT, kp, 256, 1024, 4, 1.0f);
  gemm_bt<1,1,1,1><<<242, 256, 0, stream>>>(value, wvT, vp, 256, 1024, 4, 1.0f);

  attn_kernel<<<4096, 256, 0, stream>>>(qp, kp, vp, rel, ao);

  gemm_bt<2,0,0,3><<<968, 256, 0, stream>>>(ao, woT, d_out, 1024, 1024, 0, 1.0f);
}

// Round 7
// 301.760 us; speedup vs baseline: 1.0895x; 1.0127x over previous
//
#include <hip/hip_runtime.h>
#include <hip/hip_bf16.h>

typedef __attribute__((ext_vector_type(8))) short short8;
typedef __attribute__((ext_vector_type(4))) float f32x4;
typedef __attribute__((ext_vector_type(4))) unsigned uintx4;

#define B_  32
#define S_  484
#define E_  1024
#define NH  16
#define SP  512          // padded sequence length
#define M_  (B_*S_)      // 15488 = 121*128

static __device__ __forceinline__ ushort f2bf(float f) {
  union { float f; unsigned u; } v; v.f = f;
  unsigned u = v.u;
  return (ushort)((u + 0x7FFFu + ((u >> 16) & 1u)) >> 16);
}

static __device__ __forceinline__ unsigned cvt_pk_bf16(float lo, float hi) {
  unsigned r;
  asm("v_cvt_pk_bf16_f32 %0, %1, %2" : "=v"(r) : "v"(lo), "v"(hi));
  return r;
}

#define GLOAD_LDS16(gp, lp) \
  __builtin_amdgcn_global_load_lds((const __attribute__((address_space(1))) void*)(gp), \
                                   (__attribute__((address_space(3))) void*)(lp), 16, 0, 0)

// ---------------- weight transpose + convert: WT[n][k] = W[k][n] ----------------
__global__ __launch_bounds__(256)
void transpose_convert(const float* __restrict__ W, ushort* __restrict__ WT, int K, int N) {
  __shared__ float tile[32][33];
  int k0 = blockIdx.y * 32, n0 = blockIdx.x * 32;
  int tx = threadIdx.x, ty = threadIdx.y;   // 32 x 8
  for (int i = ty; i < 32; i += 8) tile[i][tx] = W[(size_t)(k0 + i) * N + n0 + tx];
  __syncthreads();
  for (int i = ty; i < 32; i += 8) WT[(size_t)(n0 + i) * K + k0 + tx] = f2bf(tile[tx][i]);
}

// ============ BIG GEMM: 256x256 tile, 512 threads, 1 block/CU regime ============
// M=15488 (padded to 61*256 with clamped loads + guarded stores), N=K=1024.
// AF32: A is f32, reg-staged (float4 -> cvt_pk -> ds_write); else bf16 global_load_lds.
// EPI 0: bf16 out (scaled), ((b*NH+h)*SP + pos)*64 + (n&63)     (qp, no swizzle)
// EPI 2: f32 out, row-major [M][1024]
template<int EPI, int AF32>
__global__ __launch_bounds__(512)
void gemm_big(const void* __restrict__ Ain, const ushort* __restrict__ BT,
              void* __restrict__ Cout, float oscale) {
  const int K = 1024, N = 1024, NK = 32;
  __shared__ alignas(16) ushort sA[2][256 * 32];
  __shared__ alignas(16) ushort sB[2][256 * 32];
  const int tid = threadIdx.x;
  const int lane = tid & 63, w = tid >> 6;        // 8 waves
  const int m0 = (blockIdx.x >> 2) * 256;         // 61 m-tiles
  const int n0 = (blockIdx.x & 3) * 256;          // 4 n-tiles

  // B staging: 4 threads/row (32 ushorts), 2 issues cover 256 rows
  const int brow = tid >> 2, bcol = (tid & 3) * 8;
  const ushort* gB0 = BT + (size_t)(n0 + brow) * K + bcol;
  const int dstB = tid * 8;                       // ushort idx; +4096 for issue 1

  // A bf16 staging (EPI2): clamp pad rows to M_-1 (in-bounds, discarded by store guard)
  const int rowA0 = min(m0 + brow, M_ - 1);
  const int rowA1 = min(m0 + brow + 128, M_ - 1);
  const ushort* gA0bf = (const ushort*)Ain + (size_t)rowA0 * K + bcol;
  const ushort* gA1bf = (const ushort*)Ain + (size_t)rowA1 * K + bcol;

  // A f32 reg-staging (AF32): 2 threads/row, 16 floats each
  const int rowAf = min(m0 + (tid >> 1), M_ - 1);
  const float* gA0f = (const float*)Ain + (size_t)rowAf * K + (tid & 1) * 16;
  const int dstAf = (tid >> 1) * 32 + (tid & 1) * 16;   // ushort idx

  const int wr = w >> 2, wc = w & 3;              // 2x4 wave grid, each 128x64
  const int g4 = lane >> 4, l16 = lane & 15;

  f32x4 acc[8][4] = {};
  float4 fA0, fA1, fA2, fA3;

  auto issueA = [&](int kt) {
    const float4* p = (const float4*)(gA0f + kt * 32);
    fA0 = p[0]; fA1 = p[1]; fA2 = p[2]; fA3 = p[3];
  };
  auto writeA = [&](int buf) {
    unsigned d0 = cvt_pk_bf16(fA0.x, fA0.y), d1 = cvt_pk_bf16(fA0.z, fA0.w);
    unsigned d2 = cvt_pk_bf16(fA1.x, fA1.y), d3 = cvt_pk_bf16(fA1.z, fA1.w);
    unsigned d4 = cvt_pk_bf16(fA2.x, fA2.y), d5 = cvt_pk_bf16(fA2.z, fA2.w);
    unsigned d6 = cvt_pk_bf16(fA3.x, fA3.y), d7 = cvt_pk_bf16(fA3.z, fA3.w);
    ushort* dst = &sA[buf][dstAf];
    uintx4 q0 = {d0, d1, d2, d3}, q1 = {d4, d5, d6, d7};
    *(uintx4*)dst = q0;
    *(uintx4*)(dst + 8) = q1;
  };
  auto stage = [&](int kt, int buf) {
    GLOAD_LDS16(gB0 + kt * 32,           &sB[buf][dstB]);
    GLOAD_LDS16(gB0 + kt * 32 + 128 * K, &sB[buf][dstB + 4096]);
    if (AF32) issueA(kt);
    else {
      GLOAD_LDS16(gA0bf + kt * 32, &sA[buf][dstB]);
      GLOAD_LDS16(gA1bf + kt * 32, &sA[buf][dstB + 4096]);
    }
  };

  stage(0, 0);
  if (AF32) writeA(0);

  for (int kt = 0; kt < NK; ++kt) {
    __syncthreads();                 // publishes tile kt; buf[nb] free
    const int nb = (kt + 1) & 1;
    if (kt + 1 < NK) stage(kt + 1, nb);
    const ushort* pa = &sA[kt & 1][(wr * 128 + l16) * 32 + 8 * g4];
    const ushort* pb = &sB[kt & 1][(wc * 64 + l16) * 32 + 8 * g4];
    short8 af[8], bf[4];
#pragma unroll
    for (int i = 0; i < 8; ++i) af[i] = *(const short8*)(pa + i * 16 * 32);
#pragma unroll
    for (int i = 0; i < 4; ++i) bf[i] = *(const short8*)(pb + i * 16 * 32);
#pragma unroll
    for (int mi = 0; mi < 8; ++mi)
#pragma unroll
      for (int ni = 0; ni < 4; ++ni)
        acc[mi][ni] = __builtin_amdgcn_mfma_f32_16x16x32_bf16(af[mi], bf[ni], acc[mi][ni], 0, 0, 0);
    if (AF32 && kt + 1 < NK) writeA(nb);   // cvt+write after MFMAs (loads landed under compute)
  }

#pragma unroll
  for (int mi = 0; mi < 8; ++mi) {
#pragma unroll
    for (int ni = 0; ni < 4; ++ni) {
#pragma unroll
      for (int r = 0; r < 4; ++r) {
        int m = m0 + wr * 128 + mi * 16 + g4 * 4 + r;
        int n = n0 + wc * 64 + ni * 16 + l16;
        if (m < M_) {
          float vv = acc[mi][ni][r];
          if (EPI == 2) {
            ((float*)Cout)[(size_t)m * N + n] = vv;
          } else {
            int b = m / S_, pos = m % S_;
            ushort hv = f2bf(vv * oscale);
            ((ushort*)Cout)[(((size_t)b * NH + (n >> 6)) * SP + pos) * 64 + (n & 63)] = hv;
          }
        }
      }
    }
  }
}

// ---------------- 128x128 GEMM (K/V projections), XCD-chunked 1D grid ----------------
// EPI 0: bf16 out (scaled), ((b*HN+h)*SP + pos)*64 + d   [SWZ: d ^= (pos&7)<<3]
// EPI 1: bf16 out (V), ((b*HN+h)*64 + d)*SP + permuted pos [SWZ: sigma + granule xor]
template<int EPI, int SWZ, int AF32, int NXLOG>
__global__ __launch_bounds__(256)
void gemm_bt(const void* __restrict__ Ain, const ushort* __restrict__ BT,
             void* __restrict__ Cout, int N, int K, int HN, float oscale) {
  __shared__ alignas(16) ushort sA[2][128 * 32];
  __shared__ alignas(16) ushort sB[2][128 * 32];
  const int tid = threadIdx.x;
  const int lane = tid & 63, w = tid >> 6;

  const int nwg = gridDim.x;
  const int qq = nwg >> 3, rr = nwg & 7;
  const int x = blockIdx.x & 7, seq = blockIdx.x >> 3;
  const int logical = x * qq + (x < rr ? x : rr) + seq;
  const int m0 = (logical >> NXLOG) * 128;
  const int n0 = (logical & ((1 << NXLOG) - 1)) * 128;
  const int NK = K >> 5;

  const int srow = w * 32 + (lane >> 2);
  const int scol = (lane & 3) * 8;
  const ushort* gB0 = BT + (size_t)(n0 + srow) * K + scol;

  const ushort* gA0bf = (const ushort*)Ain + (size_t)(m0 + srow) * K + scol;
  const int arow = w * 32 + (lane >> 1);
  const int acol = (lane & 1) * 16;
  const float* gA0f = (const float*)Ain + (size_t)(m0 + arow) * K + acol;

  const int wr = w >> 1, wc = w & 1;
  const int g4 = lane >> 4, l16 = lane & 15;
  const int aoff = (wr * 64 + l16) * 32 + 8 * g4;
  const int boff = (wc * 64 + l16) * 32 + 8 * g4;

  f32x4 acc[4][4] = {};
  float4 fA0, fA1, fA2, fA3;

  auto issueA = [&](int kt) {
    const float4* p = (const float4*)(gA0f + kt * 32);
    fA0 = p[0]; fA1 = p[1]; fA2 = p[2]; fA3 = p[3];
  };
  auto writeA = [&](int buf) {
    unsigned d0 = cvt_pk_bf16(fA0.x, fA0.y), d1 = cvt_pk_bf16(fA0.z, fA0.w);
    unsigned d2 = cvt_pk_bf16(fA1.x, fA1.y), d3 = cvt_pk_bf16(fA1.z, fA1.w);
    unsigned d4 = cvt_pk_bf16(fA2.x, fA2.y), d5 = cvt_pk_bf16(fA2.z, fA2.w);
    unsigned d6 = cvt_pk_bf16(fA3.x, fA3.y), d7 = cvt_pk_bf16(fA3.z, fA3.w);
    ushort* dst = &sA[buf][arow * 32 + acol];
    uintx4 q0 = {d0, d1, d2, d3}, q1 = {d4, d5, d6, d7};
    *(uintx4*)dst = q0;
    *(uintx4*)(dst + 8) = q1;
  };

  if (AF32) issueA(0);
  else {
    GLOAD_LDS16(gA0bf,          &sA[0][(w * 32) * 32]);
    GLOAD_LDS16(gA0bf + 16 * K, &sA[0][(w * 32 + 16) * 32]);
  }
  GLOAD_LDS16(gB0,          &sB[0][(w * 32) * 32]);
  GLOAD_LDS16(gB0 + 16 * K, &sB[0][(w * 32 + 16) * 32]);
  if (AF32) writeA(0);

  for (int kt = 0; kt < NK; ++kt) {
    __syncthreads();
    const int nb = (kt + 1) & 1;
    if (kt + 1 < NK) {
      const ushort* gb = gB0 + (kt + 1) * 32;
      GLOAD_LDS16(gb,          &sB[nb][(w * 32) * 32]);
      GLOAD_LDS16(gb + 16 * K, &sB[nb][(w * 32 + 16) * 32]);
      if (AF32) issueA(kt + 1);
      else {
        const ushort* ga = gA0bf + (kt + 1) * 32;
        GLOAD_LDS16(ga,          &sA[nb][(w * 32) * 32]);
        GLOAD_LDS16(ga + 16 * K, &sA[nb][(w * 32 + 16) * 32]);
      }
    }
    const ushort* pa = &sA[kt & 1][aoff];
    const ushort* pb = &sB[kt & 1][boff];
    short8 af[4], bf[4];
#pragma unroll
    for (int i = 0; i < 4; ++i) {
      af[i] = *(const short8*)(pa + i * 16 * 32);
      bf[i] = *(const short8*)(pb + i * 16 * 32);
    }
#pragma unroll
    for (int mi = 0; mi < 4; ++mi)
#pragma unroll
      for (int ni = 0; ni < 4; ++ni)
        acc[mi][ni] = __builtin_amdgcn_mfma_f32_16x16x32_bf16(af[mi], bf[ni], acc[mi][ni], 0, 0, 0);
    if (AF32 && kt + 1 < NK) writeA(nb);
  }

#pragma unroll
  for (int mi = 0; mi < 4; ++mi) {
#pragma unroll
    for (int ni = 0; ni < 4; ++ni) {
#pragma unroll
      for (int r = 0; r < 4; ++r) {
        int m = m0 + wr * 64 + mi * 16 + g4 * 4 + r;
        int n = n0 + wc * 64 + ni * 16 + l16;
        float vv = acc[mi][ni][r];
        int b = m / S_, pos = m % S_;
        if (EPI == 0) {
          int dd = n & 63;
          if (SWZ) dd ^= (pos & 7) << 3;      // K-LDS row bank swizzle
          ushort hv = f2bf(vv * oscale);
          ((ushort*)Cout)[(((size_t)b * HN + (n >> 6)) * SP + pos) * 64 + dd] = hv;
        } else {
          int local = pos & 31;
          int j = (local < 16) ? (2 * local) : (2 * local - 31);
          int pf_ = (pos & ~31) | (j ^ ((n & 3) << 3));   // sigma + granule bank swizzle
          ushort hv = f2bf(vv);
          ((ushort*)Cout)[(((size_t)b * HN + (n >> 6)) * 64 + (n & 63)) * SP + pf_] = hv;
        }
      }
    }
  }
}

// ---------------- fused GQA attention: LDS-staged K/V, packed P path ----------------
__global__ __launch_bounds__(256)
void attn_kernel(const ushort* __restrict__ qp, const ushort* __restrict__ kp,
                 const ushort* __restrict__ vpT, const float* __restrict__ rel,
                 ushort* __restrict__ ao) {
  __shared__ float sBias[1056];                   // +32 guard offset
  __shared__ alignas(16) ushort sK[2][32 * 64];
  __shared__ alignas(16) ushort sV[2][64 * 32];
  __shared__ alignas(16) ushort sP[4][16 * 40];
  const int tid = threadIdx.x;
  const int blk = blockIdx.x;
  const int logical = (blk & 7) * 512 + (blk >> 3);     // bijective (4096 = 8*512)
  const int qt = logical & 7, head = (logical >> 3) & 15, b = logical >> 7;
  const int g = head >> 2;
  const float LOG2E = 1.44269504f;
  for (int t = tid; t < 1056; t += 256)
    sBias[t] = (t >= 32 && t < 999) ? rel[(t - 32) * 16 + head] * LOG2E : -1e30f;

  const int lane = tid & 63, w = tid >> 6;
  const int g4 = lane >> 4, l16 = lane & 15;
  const int qw = qt * 64 + w * 16;

  const ushort* qbase = qp + (((size_t)b * NH + head) * SP + qw + l16) * 64;
  short8 qf0 = *(const short8*)(qbase + 8 * g4);
  short8 qf1 = *(const short8*)(qbase + 32 + 8 * g4);

  const ushort* kSrc = kp  + ((size_t)b * 4 + g) * SP * 64 + (tid >> 3) * 64 + (tid & 7) * 8;
  const ushort* vSrc = vpT + ((size_t)b * 4 + g) * 64 * SP + (tid >> 2) * SP + (tid & 3) * 8;

  f32x4 acc[4] = {};
  float ps[4] = {0.f, 0.f, 0.f, 0.f};
  const int ib = l16 - (qw + g4 * 4) + 483 + 32;
  ushort* sPw = &sP[w][0];

  const int kswz  = (l16 & 7) << 3;
  const int kOff0 = l16 * 64 + ((8 * g4) ^ kswz);
  const int kOff1 = l16 * 64 + ((32 + 8 * g4) ^ kswz);
  const int vOff  = l16 * 32 + 8 * (g4 ^ (l16 & 3));

  GLOAD_LDS16(kSrc, &sK[0][w * 512]);
  GLOAD_LDS16(vSrc, &sV[0][w * 512]);

  for (int kt = 0; kt < 16; ++kt) {
    __syncthreads();
    if (kt + 1 < 16) {
      GLOAD_LDS16(kSrc + (kt + 1) * 2048, &sK[(kt + 1) & 1][w * 512]);
      GLOAD_LDS16(vSrc + (kt + 1) * 32,   &sV[(kt + 1) & 1][w * 512]);
    }
    const ushort* sk = &sK[kt & 1][0];
    const ushort* sv = &sV[kt & 1][0];
    short8 kf0 = *(const short8*)(sk + kOff0);
    short8 kf1 = *(const short8*)(sk + kOff1);
    short8 kf2 = *(const short8*)(sk + 1024 + kOff0);
    short8 kf3 = *(const short8*)(sk + 1024 + kOff1);
    f32x4 s0 = {}, s1 = {};
    s0 = __builtin_amdgcn_mfma_f32_16x16x32_bf16(qf0, kf0, s0, 0, 0, 0);
    s0 = __builtin_amdgcn_mfma_f32_16x16x32_bf16(qf1, kf1, s0, 0, 0, 0);
    s1 = __builtin_amdgcn_mfma_f32_16x16x32_bf16(qf0, kf2, s1, 0, 0, 0);
    s1 = __builtin_amdgcn_mfma_f32_16x16x32_bf16(qf1, kf3, s1, 0, 0, 0);

    const int k0 = kt * 32;
#pragma unroll
    for (int r = 0; r < 4; ++r) {
      int i0 = ib + k0 - r;
      float p0 = __builtin_amdgcn_exp2f(s0[r] + sBias[i0]);
      float p1 = __builtin_amdgcn_exp2f(s1[r] + sBias[i0 + 16]);
      if (kt == 15) {                       // mask BEFORE store: pad P == 0 exactly
        p0 = (k0 + l16 < S_) ? p0 : 0.f;
        p1 = (k0 + 16 + l16 < S_) ? p1 : 0.f;
      }
      ps[r] += p0 + p1;
      *(unsigned*)(sPw + (g4 * 4 + r) * 40 + 2 * l16) = cvt_pk_bf16(p0, p1);
    }
    short8 pf = *(const short8*)(sPw + l16 * 40 + 8 * g4);
#pragma unroll
    for (int nt = 0; nt < 4; ++nt) {
      short8 vf = *(const short8*)(sv + vOff + nt * 512);
      acc[nt] = __builtin_amdgcn_mfma_f32_16x16x32_bf16(pf, vf, acc[nt], 0, 0, 0);
    }
  }

#pragma unroll
  for (int off = 1; off < 16; off <<= 1) {
#pragma unroll
    for (int r = 0; r < 4; ++r) ps[r] += __shfl_xor(ps[r], off, 64);
  }

#pragma unroll
  for (int r = 0; r < 4; ++r) {
    int q_abs = qw + g4 * 4 + r;
    if (q_abs < S_) {
      float inv = 1.f / ps[r];
#pragma unroll
      for (int nt = 0; nt < 4; ++nt) {
        int dd = nt * 16 + l16;
        ao[((size_t)b * S_ + q_abs) * 1024 + head * 64 + dd] = f2bf(acc[nt][r] * inv);
      }
    }
  }
}

extern "C" void kernel_launch(void* const* d_in, const int* in_sizes, int n_in,
                              void* d_out, int out_size, void* d_ws, size_t ws_size,
                              hipStream_t stream) {
  const float* query = (const float*)d_in[0];
  const float* key   = (const float*)d_in[1];
  const float* value = (const float*)d_in[2];
  const float* Wq    = (const float*)d_in[3];
  const float* Wk    = (const float*)d_in[4];
  const float* Wv    = (const float*)d_in[5];
  const float* Wo    = (const float*)d_in[6];
  const float* rel   = (const float*)d_in[7];

  char* ws = (char*)d_ws;
  size_t off = 0;
  auto alloc = [&](size_t bytes) { char* p = ws + off; off += (bytes + 255) & ~(size_t)255; return p; };

  const size_t MEelems = (size_t)M_ * E_;             // 15,859,712
  ushort* wqT = (ushort*)alloc((size_t)1024 * 1024 * 2);
  ushort* wkT = (ushort*)alloc((size_t)256 * 1024 * 2);
  ushort* wvT = (ushort*)alloc((size_t)256 * 1024 * 2);
  ushort* woT = (ushort*)alloc((size_t)1024 * 1024 * 2);
  ushort* qp  = (ushort*)alloc((size_t)B_ * NH * SP * 64 * 2);   // 32 MB
  ushort* kp  = (ushort*)alloc((size_t)B_ * 4 * SP * 64 * 2);    // 8 MB
  ushort* vp  = (ushort*)alloc((size_t)B_ * 4 * 64 * SP * 2);    // 8 MB
  ushort* ao  = (ushort*)alloc(MEelems * 2);

  transpose_convert<<<dim3(32, 32), dim3(32, 8), 0, stream>>>(Wq, wqT, 1024, 1024);
  transpose_convert<<<dim3(8, 32),  dim3(32, 8), 0, stream>>>(Wk, wkT, 1024, 256);
  transpose_convert<<<dim3(8, 32),  dim3(32, 8), 0, stream>>>(Wv, wvT, 1024, 256);
  transpose_convert<<<dim3(32, 32), dim3(32, 8), 0, stream>>>(Wo, woT, 1024, 1024);

  const float QSCALE = 0.125f * 1.44269504f;   // fold 1/sqrt(D) and log2e into q
  gemm_big<0,1><<<244, 512, 0, stream>>>(query, wqT, qp, QSCALE);
  gemm_bt<0,1,1,1><<<242, 256, 0, stream>>>(key,   wkT, kp, 256, 1024, 4, 1.0f);
  gemm_bt<1,1,1,1><<<242, 256, 0, stream>>>(value, wvT, vp, 256, 1024, 4, 1.0f);

  attn_kernel<<<4096, 256, 0, stream>>>(qp, kp, vp, rel, ao);

  gemm_big<2,0><<<244, 512, 0, stream>>>(ao, woT, d_out, 1.0f);
}

// Round 8
// 297.388 us; speedup vs baseline: 1.1055x; 1.0147x over previous
//
#include <hip/hip_runtime.h>
#include <hip/hip_bf16.h>

typedef __attribute__((ext_vector_type(8))) short short8;
typedef __attribute__((ext_vector_type(4))) float f32x4;
typedef __attribute__((ext_vector_type(4))) unsigned uintx4;

#define B_  32
#define S_  484
#define E_  1024
#define NH  16
#define SP  512          // padded sequence length
#define M_  (B_*S_)      // 15488 = 121*128

static __device__ __forceinline__ ushort f2bf(float f) {
  union { float f; unsigned u; } v; v.f = f;
  unsigned u = v.u;
  return (ushort)((u + 0x7FFFu + ((u >> 16) & 1u)) >> 16);
}

static __device__ __forceinline__ unsigned cvt_pk_bf16(float lo, float hi) {
  unsigned r;
  asm("v_cvt_pk_bf16_f32 %0, %1, %2" : "=v"(r) : "v"(lo), "v"(hi));
  return r;
}

#define GLOAD_LDS16(gp, lp) \
  __builtin_amdgcn_global_load_lds((const __attribute__((address_space(1))) void*)(gp), \
                                   (__attribute__((address_space(3))) void*)(lp), 16, 0, 0)

// ---------------- f32 -> bf16 flat convert (vectorized) ----------------
__global__ __launch_bounds__(256)
void cvt_f32_bf16(const float* __restrict__ x, ushort* __restrict__ y, int n4) {
  int i = blockIdx.x * 256 + threadIdx.x;
  int stride = gridDim.x * 256;
  for (; i < n4; i += stride) {
    float4 v = ((const float4*)x)[i];
    ushort4 h;
    h.x = f2bf(v.x); h.y = f2bf(v.y); h.z = f2bf(v.z); h.w = f2bf(v.w);
    ((ushort4*)y)[i] = h;
  }
}

// ---------------- weight transpose + convert: WT[n][k] = W[k][n] ----------------
__global__ __launch_bounds__(256)
void transpose_convert(const float* __restrict__ W, ushort* __restrict__ WT, int K, int N) {
  __shared__ float tile[32][33];
  int k0 = blockIdx.y * 32, n0 = blockIdx.x * 32;
  int tx = threadIdx.x, ty = threadIdx.y;   // 32 x 8
  for (int i = ty; i < 32; i += 8) tile[i][tx] = W[(size_t)(k0 + i) * N + n0 + tx];
  __syncthreads();
  for (int i = ty; i < 32; i += 8) WT[(size_t)(n0 + i) * K + k0 + tx] = f2bf(tile[tx][i]);
}

// ======== counted-vmcnt GEMM: 128x128, bf16, 3-buffer depth-2 prefetch ========
// T4: loads stay in flight across barriers (vmcnt(4), never 0 in steady state).
// XCD-chunked 1D grid: all 2^NXLOG n-blocks of an m-slab on one XCD.
// EPI 0: bf16 out (scaled), ((b*NH+h)*SP + pos)*64 + (n&63)    (qp)
// EPI 2: f32 out, row-major [M][1024]                          (d_out)
template<int EPI, int NXLOG>
__global__ __launch_bounds__(256)
void gemm_cnt(const ushort* __restrict__ A, const ushort* __restrict__ BT,
              void* __restrict__ Cout, int N, int K, float oscale) {
  __shared__ alignas(16) ushort sA[3][128 * 32];
  __shared__ alignas(16) ushort sB[3][128 * 32];
  const int tid = threadIdx.x;
  const int lane = tid & 63, w = tid >> 6;

  const int nwg = gridDim.x;
  const int qq = nwg >> 3, rr = nwg & 7;
  const int x = blockIdx.x & 7, seq = blockIdx.x >> 3;
  const int logical = x * qq + (x < rr ? x : rr) + seq;
  const int m0 = (logical >> NXLOG) * 128;
  const int n0 = (logical & ((1 << NXLOG) - 1)) * 128;
  const int NK = K >> 5;

  const int srow = w * 32 + (lane >> 2);
  const int scol = (lane & 3) * 8;
  const ushort* gA0 = A  + (size_t)(m0 + srow) * K + scol;
  const ushort* gB0 = BT + (size_t)(n0 + srow) * K + scol;

  const int wr = w >> 1, wc = w & 1;          // 2x2 wave grid, each 64x64
  const int g4 = lane >> 4, l16 = lane & 15;
  const int aoff = (wr * 64 + l16) * 32 + 8 * g4;
  const int boff = (wc * 64 + l16) * 32 + 8 * g4;

  f32x4 acc[4][4] = {};

  auto stage = [&](int kt, int buf) {         // 4 vmem ops (LPS = 4)
    const ushort* ga = gA0 + kt * 32;
    const ushort* gb = gB0 + kt * 32;
    GLOAD_LDS16(ga,          &sA[buf][(w * 32) * 32]);
    GLOAD_LDS16(ga + 16 * K, &sA[buf][(w * 32 + 16) * 32]);
    GLOAD_LDS16(gb,          &sB[buf][(w * 32) * 32]);
    GLOAD_LDS16(gb + 16 * K, &sB[buf][(w * 32 + 16) * 32]);
  };

  stage(0, 0);
  stage(1, 1);

  int cur = 0;
  for (int kt = 0; kt < NK; ++kt) {
    // wait for tile kt only (stage kt+1 stays in flight across the barrier)
    if (kt + 1 < NK) asm volatile("s_waitcnt vmcnt(4)" ::: "memory");
    else             asm volatile("s_waitcnt vmcnt(0)" ::: "memory");
    asm volatile("s_waitcnt lgkmcnt(0)" ::: "memory");
    __builtin_amdgcn_s_barrier();
    if (kt + 2 < NK) {
      int nb = cur + 2; if (nb >= 3) nb -= 3;
      stage(kt + 2, nb);
    }
    const ushort* pa = &sA[cur][aoff];
    const ushort* pb = &sB[cur][boff];
    short8 af[4], bf[4];
#pragma unroll
    for (int i = 0; i < 4; ++i) {
      af[i] = *(const short8*)(pa + i * 16 * 32);
      bf[i] = *(const short8*)(pb + i * 16 * 32);
    }
#pragma unroll
    for (int mi = 0; mi < 4; ++mi)
#pragma unroll
      for (int ni = 0; ni < 4; ++ni)
        acc[mi][ni] = __builtin_amdgcn_mfma_f32_16x16x32_bf16(af[mi], bf[ni], acc[mi][ni], 0, 0, 0);
    if (++cur >= 3) cur = 0;
  }

#pragma unroll
  for (int mi = 0; mi < 4; ++mi) {
#pragma unroll
    for (int ni = 0; ni < 4; ++ni) {
#pragma unroll
      for (int r = 0; r < 4; ++r) {
        int m = m0 + wr * 64 + mi * 16 + g4 * 4 + r;
        int n = n0 + wc * 64 + ni * 16 + l16;
        float vv = acc[mi][ni][r];
        if (EPI == 2) {
          ((float*)Cout)[(size_t)m * N + n] = vv;
        } else {
          int b = m / S_, pos = m % S_;
          ushort hv = f2bf(vv * oscale);
          ((ushort*)Cout)[(((size_t)b * NH + (n >> 6)) * SP + pos) * 64 + (n & 63)] = hv;
        }
      }
    }
  }
}

// ---------------- 128x128 GEMM (K/V projections), f32 A reg-staged ----------------
// EPI 0: bf16 out (scaled), ((b*HN+h)*SP + pos)*64 + d   [SWZ: d ^= (pos&7)<<3]
// EPI 1: bf16 out (V), ((b*HN+h)*64 + d)*SP + permuted pos [SWZ: sigma + granule xor]
template<int EPI, int SWZ, int NXLOG>
__global__ __launch_bounds__(256)
void gemm_bt(const float* __restrict__ Ain, const ushort* __restrict__ BT,
             void* __restrict__ Cout, int N, int K, int HN, float oscale) {
  __shared__ alignas(16) ushort sA[2][128 * 32];
  __shared__ alignas(16) ushort sB[2][128 * 32];
  const int tid = threadIdx.x;
  const int lane = tid & 63, w = tid >> 6;

  const int nwg = gridDim.x;
  const int qq = nwg >> 3, rr = nwg & 7;
  const int x = blockIdx.x & 7, seq = blockIdx.x >> 3;
  const int logical = x * qq + (x < rr ? x : rr) + seq;
  const int m0 = (logical >> NXLOG) * 128;
  const int n0 = (logical & ((1 << NXLOG) - 1)) * 128;
  const int NK = K >> 5;

  const int srow = w * 32 + (lane >> 2);
  const int scol = (lane & 3) * 8;
  const ushort* gB0 = BT + (size_t)(n0 + srow) * K + scol;

  const int arow = w * 32 + (lane >> 1);
  const int acol = (lane & 1) * 16;
  const float* gA0f = Ain + (size_t)(m0 + arow) * K + acol;

  const int wr = w >> 1, wc = w & 1;
  const int g4 = lane >> 4, l16 = lane & 15;
  const int aoff = (wr * 64 + l16) * 32 + 8 * g4;
  const int boff = (wc * 64 + l16) * 32 + 8 * g4;

  f32x4 acc[4][4] = {};
  float4 fA0, fA1, fA2, fA3;

  auto issueA = [&](int kt) {
    const float4* p = (const float4*)(gA0f + kt * 32);
    fA0 = p[0]; fA1 = p[1]; fA2 = p[2]; fA3 = p[3];
  };
  auto writeA = [&](int buf) {
    unsigned d0 = cvt_pk_bf16(fA0.x, fA0.y), d1 = cvt_pk_bf16(fA0.z, fA0.w);
    unsigned d2 = cvt_pk_bf16(fA1.x, fA1.y), d3 = cvt_pk_bf16(fA1.z, fA1.w);
    unsigned d4 = cvt_pk_bf16(fA2.x, fA2.y), d5 = cvt_pk_bf16(fA2.z, fA2.w);
    unsigned d6 = cvt_pk_bf16(fA3.x, fA3.y), d7 = cvt_pk_bf16(fA3.z, fA3.w);
    ushort* dst = &sA[buf][arow * 32 + acol];
    uintx4 q0 = {d0, d1, d2, d3}, q1 = {d4, d5, d6, d7};
    *(uintx4*)dst = q0;
    *(uintx4*)(dst + 8) = q1;
  };

  issueA(0);
  GLOAD_LDS16(gB0,          &sB[0][(w * 32) * 32]);
  GLOAD_LDS16(gB0 + 16 * K, &sB[0][(w * 32 + 16) * 32]);
  writeA(0);

  for (int kt = 0; kt < NK; ++kt) {
    __syncthreads();
    const int nb = (kt + 1) & 1;
    if (kt + 1 < NK) {
      const ushort* gb = gB0 + (kt + 1) * 32;
      GLOAD_LDS16(gb,          &sB[nb][(w * 32) * 32]);
      GLOAD_LDS16(gb + 16 * K, &sB[nb][(w * 32 + 16) * 32]);
      issueA(kt + 1);
    }
    const ushort* pa = &sA[kt & 1][aoff];
    const ushort* pb = &sB[kt & 1][boff];
    short8 af[4], bf[4];
#pragma unroll
    for (int i = 0; i < 4; ++i) {
      af[i] = *(const short8*)(pa + i * 16 * 32);
      bf[i] = *(const short8*)(pb + i * 16 * 32);
    }
#pragma unroll
    for (int mi = 0; mi < 4; ++mi)
#pragma unroll
      for (int ni = 0; ni < 4; ++ni)
        acc[mi][ni] = __builtin_amdgcn_mfma_f32_16x16x32_bf16(af[mi], bf[ni], acc[mi][ni], 0, 0, 0);
    if (kt + 1 < NK) writeA(nb);
  }

#pragma unroll
  for (int mi = 0; mi < 4; ++mi) {
#pragma unroll
    for (int ni = 0; ni < 4; ++ni) {
#pragma unroll
      for (int r = 0; r < 4; ++r) {
        int m = m0 + wr * 64 + mi * 16 + g4 * 4 + r;
        int n = n0 + wc * 64 + ni * 16 + l16;
        float vv = acc[mi][ni][r];
        int b = m / S_, pos = m % S_;
        if (EPI == 0) {
          int dd = n & 63;
          if (SWZ) dd ^= (pos & 7) << 3;      // K-LDS row bank swizzle
          ushort hv = f2bf(vv * oscale);
          ((ushort*)Cout)[(((size_t)b * HN + (n >> 6)) * SP + pos) * 64 + dd] = hv;
        } else {
          int local = pos & 31;
          int j = (local < 16) ? (2 * local) : (2 * local - 31);
          int pf_ = (pos & ~31) | (j ^ ((n & 3) << 3));   // sigma + granule bank swizzle
          ushort hv = f2bf(vv);
          ((ushort*)Cout)[(((size_t)b * HN + (n >> 6)) * 64 + (n & 63)) * SP + pf_] = hv;
        }
      }
    }
  }
}

// ---------------- fused GQA attention: LDS-staged K/V, packed P path ----------------
__global__ __launch_bounds__(256)
void attn_kernel(const ushort* __restrict__ qp, const ushort* __restrict__ kp,
                 const ushort* __restrict__ vpT, const float* __restrict__ rel,
                 ushort* __restrict__ ao) {
  __shared__ float sBias[1056];                   // +32 guard offset
  __shared__ alignas(16) ushort sK[2][32 * 64];
  __shared__ alignas(16) ushort sV[2][64 * 32];
  __shared__ alignas(16) ushort sP[4][16 * 40];
  const int tid = threadIdx.x;
  const int blk = blockIdx.x;
  const int logical = (blk & 7) * 512 + (blk >> 3);     // bijective (4096 = 8*512)
  const int qt = logical & 7, head = (logical >> 3) & 15, b = logical >> 7;
  const int g = head >> 2;
  const float LOG2E = 1.44269504f;
  for (int t = tid; t < 1056; t += 256)
    sBias[t] = (t >= 32 && t < 999) ? rel[(t - 32) * 16 + head] * LOG2E : -1e30f;

  const int lane = tid & 63, w = tid >> 6;
  const int g4 = lane >> 4, l16 = lane & 15;
  const int qw = qt * 64 + w * 16;

  const ushort* qbase = qp + (((size_t)b * NH + head) * SP + qw + l16) * 64;
  short8 qf0 = *(const short8*)(qbase + 8 * g4);
  short8 qf1 = *(const short8*)(qbase + 32 + 8 * g4);

  const ushort* kSrc = kp  + ((size_t)b * 4 + g) * SP * 64 + (tid >> 3) * 64 + (tid & 7) * 8;
  const ushort* vSrc = vpT + ((size_t)b * 4 + g) * 64 * SP + (tid >> 2) * SP + (tid & 3) * 8;

  f32x4 acc[4] = {};
  float ps[4] = {0.f, 0.f, 0.f, 0.f};
  const int ib = l16 - (qw + g4 * 4) + 483 + 32;
  ushort* sPw = &sP[w][0];

  const int kswz  = (l16 & 7) << 3;
  const int kOff0 = l16 * 64 + ((8 * g4) ^ kswz);
  const int kOff1 = l16 * 64 + ((32 + 8 * g4) ^ kswz);
  const int vOff  = l16 * 32 + 8 * (g4 ^ (l16 & 3));

  GLOAD_LDS16(kSrc, &sK[0][w * 512]);
  GLOAD_LDS16(vSrc, &sV[0][w * 512]);

  for (int kt = 0; kt < 16; ++kt) {
    __syncthreads();
    if (kt + 1 < 16) {
      GLOAD_LDS16(kSrc + (kt + 1) * 2048, &sK[(kt + 1) & 1][w * 512]);
      GLOAD_LDS16(vSrc + (kt + 1) * 32,   &sV[(kt + 1) & 1][w * 512]);
    }
    const ushort* sk = &sK[kt & 1][0];
    const ushort* sv = &sV[kt & 1][0];
    short8 kf0 = *(const short8*)(sk + kOff0);
    short8 kf1 = *(const short8*)(sk + kOff1);
    short8 kf2 = *(const short8*)(sk + 1024 + kOff0);
    short8 kf3 = *(const short8*)(sk + 1024 + kOff1);
    f32x4 s0 = {}, s1 = {};
    s0 = __builtin_amdgcn_mfma_f32_16x16x32_bf16(qf0, kf0, s0, 0, 0, 0);
    s0 = __builtin_amdgcn_mfma_f32_16x16x32_bf16(qf1, kf1, s0, 0, 0, 0);
    s1 = __builtin_amdgcn_mfma_f32_16x16x32_bf16(qf0, kf2, s1, 0, 0, 0);
    s1 = __builtin_amdgcn_mfma_f32_16x16x32_bf16(qf1, kf3, s1, 0, 0, 0);

    const int k0 = kt * 32;
#pragma unroll
    for (int r = 0; r < 4; ++r) {
      int i0 = ib + k0 - r;
      float p0 = __builtin_amdgcn_exp2f(s0[r] + sBias[i0]);
      float p1 = __builtin_amdgcn_exp2f(s1[r] + sBias[i0 + 16]);
      if (kt == 15) {                       // mask BEFORE store: pad P == 0 exactly
        p0 = (k0 + l16 < S_) ? p0 : 0.f;
        p1 = (k0 + 16 + l16 < S_) ? p1 : 0.f;
      }
      ps[r] += p0 + p1;
      *(unsigned*)(sPw + (g4 * 4 + r) * 40 + 2 * l16) = cvt_pk_bf16(p0, p1);
    }
    short8 pf = *(const short8*)(sPw + l16 * 40 + 8 * g4);
#pragma unroll
    for (int nt = 0; nt < 4; ++nt) {
      short8 vf = *(const short8*)(sv + vOff + nt * 512);
      acc[nt] = __builtin_amdgcn_mfma_f32_16x16x32_bf16(pf, vf, acc[nt], 0, 0, 0);
    }
  }

#pragma unroll
  for (int off = 1; off < 16; off <<= 1) {
#pragma unroll
    for (int r = 0; r < 4; ++r) ps[r] += __shfl_xor(ps[r], off, 64);
  }

#pragma unroll
  for (int r = 0; r < 4; ++r) {
    int q_abs = qw + g4 * 4 + r;
    if (q_abs < S_) {
      float inv = 1.f / ps[r];
#pragma unroll
      for (int nt = 0; nt < 4; ++nt) {
        int dd = nt * 16 + l16;
        ao[((size_t)b * S_ + q_abs) * 1024 + head * 64 + dd] = f2bf(acc[nt][r] * inv);
      }
    }
  }
}

extern "C" void kernel_launch(void* const* d_in, const int* in_sizes, int n_in,
                              void* d_out, int out_size, void* d_ws, size_t ws_size,
                              hipStream_t stream) {
  const float* query = (const float*)d_in[0];
  const float* key   = (const float*)d_in[1];
  const float* value = (const float*)d_in[2];
  const float* Wq    = (const float*)d_in[3];
  const float* Wk    = (const float*)d_in[4];
  const float* Wv    = (const float*)d_in[5];
  const float* Wo    = (const float*)d_in[6];
  const float* rel   = (const float*)d_in[7];

  char* ws = (char*)d_ws;
  size_t off = 0;
  auto alloc = [&](size_t bytes) { char* p = ws + off; off += (bytes + 255) & ~(size_t)255; return p; };

  const size_t MEelems = (size_t)M_ * E_;             // 15,859,712
  ushort* qb  = (ushort*)alloc(MEelems * 2);          // query in bf16
  ushort* wqT = (ushort*)alloc((size_t)1024 * 1024 * 2);
  ushort* wkT = (ushort*)alloc((size_t)256 * 1024 * 2);
  ushort* wvT = (ushort*)alloc((size_t)256 * 1024 * 2);
  ushort* woT = (ushort*)alloc((size_t)1024 * 1024 * 2);
  ushort* qp  = (ushort*)alloc((size_t)B_ * NH * SP * 64 * 2);   // 32 MB
  ushort* kp  = (ushort*)alloc((size_t)B_ * 4 * SP * 64 * 2);    // 8 MB
  ushort* vp  = (ushort*)alloc((size_t)B_ * 4 * 64 * SP * 2);    // 8 MB
  ushort* ao  = (ushort*)alloc(MEelems * 2);

  cvt_f32_bf16<<<2048, 256, 0, stream>>>(query, qb, (int)(MEelems / 4));

  transpose_convert<<<dim3(32, 32), dim3(32, 8), 0, stream>>>(Wq, wqT, 1024, 1024);
  transpose_convert<<<dim3(8, 32),  dim3(32, 8), 0, stream>>>(Wk, wkT, 1024, 256);
  transpose_convert<<<dim3(8, 32),  dim3(32, 8), 0, stream>>>(Wv, wvT, 1024, 256);
  transpose_convert<<<dim3(32, 32), dim3(32, 8), 0, stream>>>(Wo, woT, 1024, 1024);

  const float QSCALE = 0.125f * 1.44269504f;   // fold 1/sqrt(D) and log2e into q
  gemm_cnt<0,3><<<968, 256, 0, stream>>>(qb, wqT, qp, 1024, 1024, QSCALE);
  gemm_bt<0,1,1><<<242, 256, 0, stream>>>(key,   wkT, kp, 256, 1024, 4, 1.0f);
  gemm_bt<1,1,1><<<242, 256, 0, stream>>>(value, wvT, vp, 256, 1024, 4, 1.0f);

  attn_kernel<<<4096, 256, 0, stream>>>(qp, kp, vp, rel, ao);

  gemm_cnt<2,3><<<968, 256, 0, stream>>>(ao, woT, d_out, 1024, 1024, 1.0f);
}